// Round 1
// baseline (3297.607 us; speedup 1.0000x reference)
//
#include <hip/hip_runtime.h>

#define D 64

// ---- degree: deg[col[e]] += 1 ----
__global__ void k_deg(const int* __restrict__ col, float* __restrict__ deg, int E) {
    int e = blockIdx.x * blockDim.x + threadIdx.x;
    if (e < E) unsafeAtomicAdd(&deg[col[e]], 1.0f);
}

// ---- deg -> deg^{-1/2} in place (0 stays 0) ----
__global__ void k_dis(float* __restrict__ deg, int N) {
    int i = blockIdx.x * blockDim.x + threadIdx.x;
    if (i < N) {
        float d = deg[i];
        deg[i] = (d > 0.0f) ? rsqrtf(d) : 0.0f;
    }
}

// ---- norm[e] = dis[row[e]] * dis[col[e]] ----
__global__ void k_norm(const int* __restrict__ row, const int* __restrict__ col,
                       const float* __restrict__ dis, float* __restrict__ norm, int E) {
    int e = blockIdx.x * blockDim.x + threadIdx.x;
    if (e < E) norm[e] = dis[row[e]] * dis[col[e]];
}

// ---- y[col[e]] += norm[e] * x[row[e]]  (16 threads/edge, float4 each) ----
__global__ void k_scatter(const int* __restrict__ row, const int* __restrict__ col,
                          const float* __restrict__ norm, const float* __restrict__ x,
                          float* __restrict__ y, int E) {
    int t = blockIdx.x * blockDim.x + threadIdx.x;
    int e = t >> 4;
    if (e >= E) return;
    int dq = (t & 15) << 2;
    int r = row[e];
    int c = col[e];
    float nv = norm[e];
    float4 xv = *reinterpret_cast<const float4*>(x + (size_t)r * D + dq);
    float* yp = y + (size_t)c * D + dq;
    unsafeAtomicAdd(yp + 0, nv * xv.x);
    unsafeAtomicAdd(yp + 1, nv * xv.y);
    unsafeAtomicAdd(yp + 2, nv * xv.z);
    unsafeAtomicAdd(yp + 3, nv * xv.w);
}

// ---- acc += x (vectorized) ----
__global__ void k_add(float* __restrict__ acc, const float* __restrict__ x, int n4) {
    int i = blockIdx.x * blockDim.x + threadIdx.x;
    if (i < n4) {
        float4 a = reinterpret_cast<float4*>(acc)[i];
        float4 b = reinterpret_cast<const float4*>(x)[i];
        a.x += b.x; a.y += b.y; a.z += b.z; a.w += b.w;
        reinterpret_cast<float4*>(acc)[i] = a;
    }
}

// ---- acc *= s ----
__global__ void k_scale(float* __restrict__ acc, float s, int n4) {
    int i = blockIdx.x * blockDim.x + threadIdx.x;
    if (i < n4) {
        float4 a = reinterpret_cast<float4*>(acc)[i];
        a.x *= s; a.y *= s; a.z *= s; a.w *= s;
        reinterpret_cast<float4*>(acc)[i] = a;
    }
}

extern "C" void kernel_launch(void* const* d_in, const int* in_sizes, int n_in,
                              void* d_out, int out_size, void* d_ws, size_t ws_size,
                              hipStream_t stream) {
    const float* emb = (const float*)d_in[0];
    const int*   ei  = (const int*)d_in[1];
    const int N = in_sizes[0] / D;       // 100000
    const int E = in_sizes[1] / 2;       // 1250000
    const int* row = ei;
    const int* col = ei + E;

    float* ws   = (float*)d_ws;
    float* deg  = ws;                    // N floats (becomes deg^{-1/2})
    float* norm = ws + N;                // E floats
    size_t off  = ((size_t)N + (size_t)E + 3) & ~(size_t)3;
    float* x0   = ws + off;              // N*D floats
    float* x1   = x0 + (size_t)N * D;    // N*D floats
    float* out  = (float*)d_out;

    const size_t xbytes = (size_t)N * D * sizeof(float);
    const int n4 = N * D / 4;

    // degree + norm
    hipMemsetAsync(deg, 0, (size_t)N * sizeof(float), stream);
    k_deg <<<(E + 255) / 256, 256, 0, stream>>>(col, deg, E);
    k_dis <<<(N + 255) / 256, 256, 0, stream>>>(deg, N);
    k_norm<<<(E + 255) / 256, 256, 0, stream>>>(row, col, deg, norm, E);

    // acc = emb (in d_out); x_cur = emb
    hipMemcpyAsync(out, emb, xbytes, hipMemcpyDeviceToDevice, stream);
    hipMemcpyAsync(x0,  emb, xbytes, hipMemcpyDeviceToDevice, stream);

    float* cur = x0;
    float* nxt = x1;
    const int scatter_threads_total = E * 16;   // 20M
    for (int l = 0; l < 3; ++l) {
        hipMemsetAsync(nxt, 0, xbytes, stream);
        k_scatter<<<(scatter_threads_total + 255) / 256, 256, 0, stream>>>(
            row, col, norm, cur, nxt, E);
        k_add<<<(n4 + 255) / 256, 256, 0, stream>>>(out, nxt, n4);
        float* t = cur; cur = nxt; nxt = t;
    }

    // out = acc / 4
    k_scale<<<(n4 + 255) / 256, 256, 0, stream>>>(out, 0.25f, n4);
}

// Round 2
// 492.307 us; speedup vs baseline: 6.6983x; 6.6983x over previous
//
#include <hip/hip_runtime.h>

#define D 64
#define SCAN_B 256

// ---- count: cnt[col[e]]++ (int atomics) ----
__global__ void k_count(const int* __restrict__ col, int* __restrict__ cnt, int E) {
    int e = blockIdx.x * blockDim.x + threadIdx.x;
    if (e < E) atomicAdd(&cnt[col[e]], 1);
}

// ---- dis[i] = cnt>0 ? rsqrt(cnt) : 0 ----
__global__ void k_dis(const int* __restrict__ cnt, float* __restrict__ dis, int N) {
    int i = blockIdx.x * blockDim.x + threadIdx.x;
    if (i < N) {
        int c = cnt[i];
        dis[i] = (c > 0) ? rsqrtf((float)c) : 0.0f;
    }
}

// ---- scan step 1: per-block exclusive scan of cnt -> start, block sums -> bsum ----
__global__ void k_scan1(const int* __restrict__ cnt, int* __restrict__ start,
                        int* __restrict__ bsum, int N) {
    __shared__ int tmp[SCAN_B];
    int i = blockIdx.x * SCAN_B + threadIdx.x;
    int v = (i < N) ? cnt[i] : 0;
    tmp[threadIdx.x] = v;
    __syncthreads();
    for (int off = 1; off < SCAN_B; off <<= 1) {
        int t = (threadIdx.x >= (unsigned)off) ? tmp[threadIdx.x - off] : 0;
        __syncthreads();
        tmp[threadIdx.x] += t;
        __syncthreads();
    }
    if (i < N) start[i] = tmp[threadIdx.x] - v;   // exclusive
    if (threadIdx.x == SCAN_B - 1) bsum[blockIdx.x] = tmp[SCAN_B - 1];
}

// ---- scan step 2: single-block exclusive scan of block sums (nb <= 512) ----
__global__ void k_scan2(int* __restrict__ bsum, int nb) {
    __shared__ int tmp[512];
    int v = (threadIdx.x < (unsigned)nb) ? bsum[threadIdx.x] : 0;
    tmp[threadIdx.x] = v;
    __syncthreads();
    for (int off = 1; off < 512; off <<= 1) {
        int t = (threadIdx.x >= (unsigned)off) ? tmp[threadIdx.x - off] : 0;
        __syncthreads();
        tmp[threadIdx.x] += t;
        __syncthreads();
    }
    if (threadIdx.x < (unsigned)nb) bsum[threadIdx.x] = tmp[threadIdx.x] - v;
}

// ---- scan step 3: add block offsets; set start[N] = E ----
__global__ void k_scan3(int* __restrict__ start, const int* __restrict__ bsum,
                        int N, int E) {
    int i = blockIdx.x * SCAN_B + threadIdx.x;
    if (i < N) start[i] += bsum[blockIdx.x];
    if (i == 0) start[N] = E;
}

// ---- fill CSR: slot = cursor[c]++; rown[slot]=row; normv[slot]=dis[r]*dis[c] ----
__global__ void k_fill(const int* __restrict__ row, const int* __restrict__ col,
                       const float* __restrict__ dis, int* __restrict__ cursor,
                       int* __restrict__ rown, float* __restrict__ normv, int E) {
    int e = blockIdx.x * blockDim.x + threadIdx.x;
    if (e >= E) return;
    int r = row[e], c = col[e];
    int slot = atomicAdd(&cursor[c], 1);
    rown[slot]  = r;
    normv[slot] = dis[r] * dis[c];
}

// ---- gather layer: wave per node, lane = dim; y = sum, acc += sum ----
__global__ void k_gather(const int* __restrict__ start, const int* __restrict__ rown,
                         const float* __restrict__ normv, const float* __restrict__ x,
                         float* __restrict__ y, float* __restrict__ acc, int N) {
    int node = blockIdx.x * (blockDim.x >> 6) + (threadIdx.x >> 6);
    if (node >= N) return;
    int lane = threadIdx.x & 63;
    int s  = start[node];
    int e2 = start[node + 1];
    float sum = 0.0f;
    int i = s;
    for (; i + 2 <= e2; i += 2) {
        int   r0 = rown[i],     r1 = rown[i + 1];
        float n0 = normv[i],    n1 = normv[i + 1];
        float a0 = x[(size_t)r0 * D + lane];
        float a1 = x[(size_t)r1 * D + lane];
        sum = fmaf(n0, a0, sum);
        sum = fmaf(n1, a1, sum);
    }
    if (i < e2) {
        int   r0 = rown[i];
        float n0 = normv[i];
        sum = fmaf(n0, x[(size_t)r0 * D + lane], sum);
    }
    size_t o = (size_t)node * D + lane;
    y[o] = sum;
    acc[o] += sum;
}

// ---- acc *= s ----
__global__ void k_scale(float* __restrict__ acc, float s, int n4) {
    int i = blockIdx.x * blockDim.x + threadIdx.x;
    if (i < n4) {
        float4 a = reinterpret_cast<float4*>(acc)[i];
        a.x *= s; a.y *= s; a.z *= s; a.w *= s;
        reinterpret_cast<float4*>(acc)[i] = a;
    }
}

extern "C" void kernel_launch(void* const* d_in, const int* in_sizes, int n_in,
                              void* d_out, int out_size, void* d_ws, size_t ws_size,
                              hipStream_t stream) {
    const float* emb = (const float*)d_in[0];
    const int*   ei  = (const int*)d_in[1];
    const int N = in_sizes[0] / D;       // 100000
    const int E = in_sizes[1] / 2;       // 1250000
    const int* row = ei;
    const int* col = ei + E;

    // ws layout (4-byte units)
    int*   cnt    = (int*)d_ws;                    // N   (reused as cursor after scan)
    int*   start  = cnt + N;                       // N+1
    int*   bsum   = start + N + 1;                 // 512
    int*   rown   = bsum + 512;                    // E
    float* normv  = (float*)(rown + E);            // E
    float* dis    = normv + E;                     // N
    float* x0     = dis + N;                       // N*D
    float* x1     = x0 + (size_t)N * D;            // N*D
    float* out    = (float*)d_out;

    const size_t xbytes = (size_t)N * D * sizeof(float);
    const int n4 = N * D / 4;
    const int nb = (N + SCAN_B - 1) / SCAN_B;      // 391 blocks

    // ---- CSR build ----
    hipMemsetAsync(cnt, 0, (size_t)N * sizeof(int), stream);
    k_count<<<(E + 255) / 256, 256, 0, stream>>>(col, cnt, E);
    k_dis  <<<(N + 255) / 256, 256, 0, stream>>>(cnt, dis, N);
    k_scan1<<<nb, SCAN_B, 0, stream>>>(cnt, start, bsum, N);
    k_scan2<<<1, 512, 0, stream>>>(bsum, nb);
    k_scan3<<<nb, SCAN_B, 0, stream>>>(start, bsum, N, E);
    // cursor = start (reuse cnt)
    hipMemcpyAsync(cnt, start, (size_t)N * sizeof(int), hipMemcpyDeviceToDevice, stream);
    k_fill <<<(E + 255) / 256, 256, 0, stream>>>(row, col, dis, cnt, rown, normv, E);

    // ---- acc = emb ----
    hipMemcpyAsync(out, emb, xbytes, hipMemcpyDeviceToDevice, stream);

    // ---- 3 gather layers (layer 1 reads emb directly) ----
    const int gblocks = (N + 3) / 4;               // 4 waves (nodes) per 256-thr block
    k_gather<<<gblocks, 256, 0, stream>>>(start, rown, normv, emb, x0, out, N);
    k_gather<<<gblocks, 256, 0, stream>>>(start, rown, normv, x0,  x1, out, N);
    k_gather<<<gblocks, 256, 0, stream>>>(start, rown, normv, x1,  x0, out, N);

    // ---- out = acc / 4 ----
    k_scale<<<(n4 + 255) / 256, 256, 0, stream>>>(out, 0.25f, n4);
}

// Round 5
// 440.679 us; speedup vs baseline: 7.4830x; 1.1172x over previous
//
#include <hip/hip_runtime.h>

#define D 64
#define SCAN_B 256

// ---- count: cnt[col[e]]++ ----
__global__ void k_count(const int* __restrict__ col, int* __restrict__ cnt, int E) {
    int e = blockIdx.x * blockDim.x + threadIdx.x;
    if (e < E) atomicAdd(&cnt[col[e]], 1);
}

// ---- dis[i] = cnt>0 ? rsqrt(cnt) : 0 ----
__global__ void k_dis(const int* __restrict__ cnt, float* __restrict__ dis, int N) {
    int i = blockIdx.x * blockDim.x + threadIdx.x;
    if (i < N) {
        int c = cnt[i];
        dis[i] = (c > 0) ? rsqrtf((float)c) : 0.0f;
    }
}

// ---- scan step 1: per-block exclusive scan of cnt -> start, block sums -> bsum ----
__global__ void k_scan1(const int* __restrict__ cnt, int* __restrict__ start,
                        int* __restrict__ bsum, int N) {
    __shared__ int tmp[SCAN_B];
    int i = blockIdx.x * SCAN_B + threadIdx.x;
    int v = (i < N) ? cnt[i] : 0;
    tmp[threadIdx.x] = v;
    __syncthreads();
    for (int off = 1; off < SCAN_B; off <<= 1) {
        int t = (threadIdx.x >= (unsigned)off) ? tmp[threadIdx.x - off] : 0;
        __syncthreads();
        tmp[threadIdx.x] += t;
        __syncthreads();
    }
    if (i < N) start[i] = tmp[threadIdx.x] - v;   // exclusive
    if (threadIdx.x == SCAN_B - 1) bsum[blockIdx.x] = tmp[SCAN_B - 1];
}

// ---- scan step 2: single-block exclusive scan of block sums (nb <= 512) ----
__global__ void k_scan2(int* __restrict__ bsum, int nb) {
    __shared__ int tmp[512];
    int v = (threadIdx.x < (unsigned)nb) ? bsum[threadIdx.x] : 0;
    tmp[threadIdx.x] = v;
    __syncthreads();
    for (int off = 1; off < 512; off <<= 1) {
        int t = (threadIdx.x >= (unsigned)off) ? tmp[threadIdx.x - off] : 0;
        __syncthreads();
        tmp[threadIdx.x] += t;
        __syncthreads();
    }
    if (threadIdx.x < (unsigned)nb) bsum[threadIdx.x] = tmp[threadIdx.x] - v;
}

// ---- scan step 3: add block offsets; write cursor copy; start[N] = E ----
__global__ void k_scan3(int* __restrict__ start, int* __restrict__ cursor,
                        const int* __restrict__ bsum, int N, int E) {
    int i = blockIdx.x * SCAN_B + threadIdx.x;
    if (i < N) {
        int v = start[i] + bsum[blockIdx.x];
        start[i]  = v;
        cursor[i] = v;
    }
    if (i == 0) start[N] = E;
}

// ---- fill CSR: one packed 8B store per edge ----
__global__ void k_fill(const int* __restrict__ row, const int* __restrict__ col,
                       const float* __restrict__ dis, int* __restrict__ cursor,
                       int2* __restrict__ edges, int E) {
    int e = blockIdx.x * blockDim.x + threadIdx.x;
    if (e >= E) return;
    int r = row[e], c = col[e];
    int slot = atomicAdd(&cursor[c], 1);
    edges[slot] = make_int2(r, __float_as_int(dis[r] * dis[c]));
}

// ---- gather layer: wave per node, lane = dim ----
// MODE 0: y = sum, acc = x[o] + sum       (first layer, x == emb, fuses acc init)
// MODE 1: y = sum, acc += sum             (middle layer)
// MODE 2: acc = (acc + sum) * 0.25f       (last layer, no y write, fuses scale)
template <int MODE>
__global__ void k_gather(const int* __restrict__ start, const int2* __restrict__ edges,
                         const float* __restrict__ x, float* __restrict__ y,
                         float* __restrict__ acc, int N) {
    int node = blockIdx.x * (blockDim.x >> 6) + (threadIdx.x >> 6);
    if (node >= N) return;
    int lane = threadIdx.x & 63;
    int s  = start[node];
    int e2 = start[node + 1];
    float sum = 0.0f;
    int i = s;
    for (; i + 2 <= e2; i += 2) {
        int2 a = edges[i];
        int2 b = edges[i + 1];
        float xa = x[(size_t)a.x * D + lane];
        float xb = x[(size_t)b.x * D + lane];
        sum = fmaf(__int_as_float(a.y), xa, sum);
        sum = fmaf(__int_as_float(b.y), xb, sum);
    }
    if (i < e2) {
        int2 a = edges[i];
        sum = fmaf(__int_as_float(a.y), x[(size_t)a.x * D + lane], sum);
    }
    size_t o = (size_t)node * D + lane;
    if (MODE == 0) {
        y[o] = sum;
        acc[o] = x[o] + sum;
    } else if (MODE == 1) {
        y[o] = sum;
        acc[o] += sum;
    } else {
        acc[o] = (acc[o] + sum) * 0.25f;
    }
}

extern "C" void kernel_launch(void* const* d_in, const int* in_sizes, int n_in,
                              void* d_out, int out_size, void* d_ws, size_t ws_size,
                              hipStream_t stream) {
    const float* emb = (const float*)d_in[0];
    const int*   ei  = (const int*)d_in[1];
    const int N = in_sizes[0] / D;       // 100000
    const int E = in_sizes[1] / 2;       // 1250000
    const int* row = ei;
    const int* col = ei + E;

    // ws layout (edges first for 8B alignment)
    int2*  edges  = (int2*)d_ws;                   // E int2
    int*   cnt    = (int*)(edges + E);             // N
    int*   start  = cnt + N;                       // N+1
    int*   bsum   = start + N + 1;                 // 512
    int*   cursor = bsum + 512;                    // N
    float* dis    = (float*)(cursor + N);          // N
    float* x0     = dis + N;                       // N*D
    float* x1     = x0 + (size_t)N * D;            // N*D
    float* out    = (float*)d_out;

    const int nb = (N + SCAN_B - 1) / SCAN_B;      // 391 blocks

    // ---- CSR build ----
    hipMemsetAsync(cnt, 0, (size_t)N * sizeof(int), stream);
    k_count<<<(E + 255) / 256, 256, 0, stream>>>(col, cnt, E);
    k_dis  <<<(N + 255) / 256, 256, 0, stream>>>(cnt, dis, N);
    k_scan1<<<nb, SCAN_B, 0, stream>>>(cnt, start, bsum, N);
    k_scan2<<<1, 512, 0, stream>>>(bsum, nb);
    k_scan3<<<nb, SCAN_B, 0, stream>>>(start, cursor, bsum, N, E);
    k_fill <<<(E + 255) / 256, 256, 0, stream>>>(row, col, dis, cursor, edges, E);

    // ---- 3 gather layers (acc init and final scale fused) ----
    const int gblocks = (N + 3) / 4;               // 4 nodes per 256-thread block
    k_gather<0><<<gblocks, 256, 0, stream>>>(start, edges, emb, x0, out, N);
    k_gather<1><<<gblocks, 256, 0, stream>>>(start, edges, x0,  x1, out, N);
    k_gather<2><<<gblocks, 256, 0, stream>>>(start, edges, x1, nullptr, out, N);
}

// Round 6
// 416.361 us; speedup vs baseline: 7.9201x; 1.0584x over previous
//
#include <hip/hip_runtime.h>
#include <hip/hip_fp16.h>

#define D 64
#define SCAN_B 256

// ---- count: cnt[col[e]]++ ----
__global__ void k_count(const int* __restrict__ col, int* __restrict__ cnt, int E) {
    int e = blockIdx.x * blockDim.x + threadIdx.x;
    if (e < E) atomicAdd(&cnt[col[e]], 1);
}

// ---- dis[i] = cnt>0 ? rsqrt(cnt) : 0 ----
__global__ void k_dis(const int* __restrict__ cnt, float* __restrict__ dis, int N) {
    int i = blockIdx.x * blockDim.x + threadIdx.x;
    if (i < N) {
        int c = cnt[i];
        dis[i] = (c > 0) ? rsqrtf((float)c) : 0.0f;
    }
}

// ---- scan step 1 ----
__global__ void k_scan1(const int* __restrict__ cnt, int* __restrict__ start,
                        int* __restrict__ bsum, int N) {
    __shared__ int tmp[SCAN_B];
    int i = blockIdx.x * SCAN_B + threadIdx.x;
    int v = (i < N) ? cnt[i] : 0;
    tmp[threadIdx.x] = v;
    __syncthreads();
    for (int off = 1; off < SCAN_B; off <<= 1) {
        int t = (threadIdx.x >= (unsigned)off) ? tmp[threadIdx.x - off] : 0;
        __syncthreads();
        tmp[threadIdx.x] += t;
        __syncthreads();
    }
    if (i < N) start[i] = tmp[threadIdx.x] - v;   // exclusive
    if (threadIdx.x == SCAN_B - 1) bsum[blockIdx.x] = tmp[SCAN_B - 1];
}

// ---- scan step 2 (nb <= 512) ----
__global__ void k_scan2(int* __restrict__ bsum, int nb) {
    __shared__ int tmp[512];
    int v = (threadIdx.x < (unsigned)nb) ? bsum[threadIdx.x] : 0;
    tmp[threadIdx.x] = v;
    __syncthreads();
    for (int off = 1; off < 512; off <<= 1) {
        int t = (threadIdx.x >= (unsigned)off) ? tmp[threadIdx.x - off] : 0;
        __syncthreads();
        tmp[threadIdx.x] += t;
        __syncthreads();
    }
    if (threadIdx.x < (unsigned)nb) bsum[threadIdx.x] = tmp[threadIdx.x] - v;
}

// ---- scan step 3: add offsets; cursor copy; start[N]=E ----
__global__ void k_scan3(int* __restrict__ start, int* __restrict__ cursor,
                        const int* __restrict__ bsum, int N, int E) {
    int i = blockIdx.x * SCAN_B + threadIdx.x;
    if (i < N) {
        int v = start[i] + bsum[blockIdx.x];
        start[i]  = v;
        cursor[i] = v;
    }
    if (i == 0) start[N] = E;
}

// ---- fill CSR: one 4B scattered store per edge (row only) ----
__global__ void k_fill(const int* __restrict__ row, const int* __restrict__ col,
                       int* __restrict__ cursor, int* __restrict__ rown, int E) {
    int e = blockIdx.x * blockDim.x + threadIdx.x;
    if (e >= E) return;
    int r = row[e], c = col[e];
    int slot = atomicAdd(&cursor[c], 1);
    rown[slot] = r;
}

// ---- z0 = fp16(dis[node] * emb), 2 elems/thread ----
__global__ void k_zconv(const float* __restrict__ emb, const float* __restrict__ dis,
                        __half2* __restrict__ z, int n2) {
    int idx = blockIdx.x * blockDim.x + threadIdx.x;
    if (idx >= n2) return;
    float2 e = reinterpret_cast<const float2*>(emb)[idx];
    float dv = dis[idx >> 5];                    // node = (idx*2)/64
    z[idx] = __floats2half2_rn(dv * e.x, dv * e.y);
}

// ---- gather layer: wave per node, lane = dim ----
// sum = sum_{r in N(c)} z[r];  y = dis[c]*sum;  z_next = dis[c]*y (fp16)
// MODE 0: acc = emb + y   MODE 1: acc += y   MODE 2: acc = (acc+y)*0.25, no z_next
template <int MODE>
__global__ void k_gather(const int* __restrict__ start, const int* __restrict__ rown,
                         const __half* __restrict__ z, const float* __restrict__ dis,
                         const float* __restrict__ emb, __half* __restrict__ znext,
                         float* __restrict__ acc, int N) {
    int node = blockIdx.x * (blockDim.x >> 6) + (threadIdx.x >> 6);
    if (node >= N) return;
    int lane = threadIdx.x & 63;
    int s  = start[node];
    int e2 = start[node + 1];
    float sum = 0.0f;
    int i = s;
    for (; i + 4 <= e2; i += 4) {
        int r0 = rown[i], r1 = rown[i + 1], r2 = rown[i + 2], r3 = rown[i + 3];
        float a0 = __half2float(z[(size_t)r0 * D + lane]);
        float a1 = __half2float(z[(size_t)r1 * D + lane]);
        float a2 = __half2float(z[(size_t)r2 * D + lane]);
        float a3 = __half2float(z[(size_t)r3 * D + lane]);
        sum += (a0 + a1) + (a2 + a3);
    }
    for (; i < e2; ++i) {
        sum += __half2float(z[(size_t)rown[i] * D + lane]);
    }
    float dc = dis[node];
    float y = dc * sum;
    size_t o = (size_t)node * D + lane;
    if (MODE == 0) {
        acc[o] = emb[o] + y;
        znext[o] = __float2half_rn(dc * y);
    } else if (MODE == 1) {
        acc[o] += y;
        znext[o] = __float2half_rn(dc * y);
    } else {
        acc[o] = (acc[o] + y) * 0.25f;
    }
}

extern "C" void kernel_launch(void* const* d_in, const int* in_sizes, int n_in,
                              void* d_out, int out_size, void* d_ws, size_t ws_size,
                              hipStream_t stream) {
    const float* emb = (const float*)d_in[0];
    const int*   ei  = (const int*)d_in[1];
    const int N = in_sizes[0] / D;       // 100000
    const int E = in_sizes[1] / 2;       // 1250000
    const int* row = ei;
    const int* col = ei + E;

    // ws layout (4-byte units unless noted)
    int*    rown   = (int*)d_ws;                    // E
    int*    cnt    = rown + E;                      // N
    int*    start  = cnt + N;                       // N+1
    int*    bsum   = start + N + 1;                 // 512
    int*    cursor = bsum + 512;                    // N
    float*  dis    = (float*)(cursor + N);          // N
    __half* z0     = (__half*)(dis + N);            // N*D halves
    __half* z1     = z0 + (size_t)N * D;            // N*D halves
    float*  out    = (float*)d_out;

    const int nb = (N + SCAN_B - 1) / SCAN_B;       // blocks for scan over N

    // ---- CSR build ----
    hipMemsetAsync(cnt, 0, (size_t)N * sizeof(int), stream);
    k_count<<<(E + 255) / 256, 256, 0, stream>>>(col, cnt, E);
    k_dis  <<<(N + 255) / 256, 256, 0, stream>>>(cnt, dis, N);
    k_scan1<<<nb, SCAN_B, 0, stream>>>(cnt, start, bsum, N);
    k_scan2<<<1, 512, 0, stream>>>(bsum, nb);
    k_scan3<<<nb, SCAN_B, 0, stream>>>(start, cursor, bsum, N, E);
    k_fill <<<(E + 255) / 256, 256, 0, stream>>>(row, col, cursor, rown, E);

    // ---- z0 = fp16(dis * emb) ----
    const int n2 = N * D / 2;
    k_zconv<<<(n2 + 255) / 256, 256, 0, stream>>>(emb, dis, (__half2*)z0, n2);

    // ---- 3 gather layers (acc init and final scale fused) ----
    const int gblocks = (N + 3) / 4;                // 4 nodes per 256-thread block
    k_gather<0><<<gblocks, 256, 0, stream>>>(start, rown, z0, dis, emb, z1, out, N);
    k_gather<1><<<gblocks, 256, 0, stream>>>(start, rown, z1, dis, nullptr, z0, out, N);
    k_gather<2><<<gblocks, 256, 0, stream>>>(start, rown, z0, dis, nullptr, nullptr, out, N);
}